// Round 6
// baseline (153.967 us; speedup 1.0000x reference)
//
#include <hip/hip_runtime.h>
#include <cstdint>

// ---------------------------------------------------------------------------
// CausalSelfAttention: S=2048, D=1024, H=16, HS=64
// Split-K flash attention (S^T orientation, 128-query blocks, no-max softmax,
// ones-MFMA rowsum, double-buffered K/V, XOR-swizzled LDS, head->XCD pinning)
// + bf16 MFMA GEMMs (BK=64, swizzled LDS).
// ---------------------------------------------------------------------------

typedef __bf16 bf16;
typedef __attribute__((ext_vector_type(4))) float f32x4;
typedef __attribute__((ext_vector_type(8))) bf16 bf16x8;
typedef __attribute__((ext_vector_type(4))) bf16 bf16x4;

#define S_LEN 2048
#define D_DIM 1024
#define NH 16
#define HS 64
#define CHUNK 8          // K-tiles (of 64 keys) per split-K chunk
#define NCK 4            // max chunks = 32 ktiles / CHUNK

__device__ __forceinline__ bf16 f2bf(float f) {
  uint32_t u = __builtin_bit_cast(uint32_t, f);
  uint32_t r = (u + 0x7FFFu + ((u >> 16) & 1u)) >> 16;
  unsigned short s = (unsigned short)r;
  return __builtin_bit_cast(bf16, s);
}

__device__ __forceinline__ void load_lds16(const void* g, void* l) {
  __builtin_amdgcn_global_load_lds(
      (__attribute__((address_space(1))) unsigned int*)(uintptr_t)g,
      (__attribute__((address_space(3))) unsigned int*)l, 16, 0, 0);
}

// pack two fp32 -> bf16 pair with round-half-up: (hi<<16)|lo
__device__ __forceinline__ uint32_t pack_bf16(float lo, float hi) {
  uint32_t a = __builtin_bit_cast(uint32_t, lo) + 0x8000u;
  uint32_t b = __builtin_bit_cast(uint32_t, hi) + 0x8000u;
  return __builtin_amdgcn_perm(b, a, 0x07060302u);
}

// ---------------------------------------------------------------------------
// Fused prep: blocks [0,2048): cast hs -> hsb (bf16)
//             blocks [2048,6144): transpose+cast W_attn / W_proj
// ---------------------------------------------------------------------------
__global__ __launch_bounds__(256) void prep_kernel(
    const float* __restrict__ hs, const float* __restrict__ Wa,
    const float* __restrict__ Wp, bf16* __restrict__ hsb,
    bf16* __restrict__ WaT, bf16* __restrict__ WpT) {
  const int bid = blockIdx.x;
  if (bid < 2048) {
    const int i = bid * 256 + threadIdx.x;
    float4 v = ((const float4*)hs)[i];
    bf16x4 o;
    o[0] = f2bf(v.x); o[1] = f2bf(v.y); o[2] = f2bf(v.z); o[3] = f2bf(v.w);
    ((bf16x4*)hsb)[i] = o;
    return;
  }
  __shared__ float tile[32][33];
  const int tb = bid - 2048;          // [0,4096)
  const int bx = tb & 127;            // col-tile: Wa 0..95, Wp 96..127
  const int r0 = (tb >> 7) * 32;      // row-tile (R = 1024 both)
  const bool isA = bx < 96;
  const float* in = isA ? Wa : Wp;
  bf16* out = isA ? WaT : WpT;
  const int C = isA ? 3072 : 1024;
  const int c0 = (isA ? bx : bx - 96) * 32;
  const int x = threadIdx.x & 31, y = threadIdx.x >> 5;
  for (int k = 0; k < 32; k += 8)
    tile[y + k][x] = in[(size_t)(r0 + y + k) * C + c0 + x];
  __syncthreads();
  for (int k = 0; k < 32; k += 8)
    out[(size_t)(c0 + y + k) * 1024 + r0 + x] = f2bf(tile[x][y + k]);
}

// ---------------------------------------------------------------------------
// GEMM: C[M][N] = A[M][K] * Bt[N][K]^T + bias[N].  BK=64, XOR-swizzled LDS
// (16B granule slot g holds source granule g^(row&7) -> 2-way reads, free).
// MODE 0: fp32 out. MODE 2: bf16 qkv out, but blocks with n0 >= 2*D_DIM write
// V transposed into VtOut[col-2048][row] instead.
// BM=BN=128: 2x2 waves of 64x64 (4x4). BM=128,BN=64: 4x1 waves of 32x64 (2x4).
// ---------------------------------------------------------------------------
template <int BM, int BN, int MODE>
__global__ __launch_bounds__(256) void gemm_bt_kernel(
    const bf16* __restrict__ A, const bf16* __restrict__ Bt,
    const float* __restrict__ bias, void* __restrict__ Cout,
    bf16* __restrict__ VtOut, int M, int N, int K) {
  constexpr int MI = (BN == 128) ? 4 : 2;
  constexpr int NI = 4;
  __shared__ bf16 As[BM * 64];
  __shared__ bf16 Bs[BN * 64];
  const int t = threadIdx.x;
  const int wave = t >> 6;
  const int lane = t & 63;
  const int quad = lane >> 4;
  const int l16 = lane & 15;
  const int m0 = blockIdx.y * BM;
  const int n0 = blockIdx.x * BN;
  const int wm = (BN == 128) ? (wave >> 1) * 64 : wave * 32;
  const int wn = (BN == 128) ? (wave & 1) * 64 : 0;

  f32x4 acc[MI][NI];
  for (int i = 0; i < MI; i++)
    for (int j = 0; j < NI; j++)
      for (int r = 0; r < 4; r++) acc[i][j][r] = 0.f;

  // staging: 8 threads/row of 64 cols, 32 rows per issue, swizzled source col
  const int srow = t >> 3;                        // 0..31
  const int gcol = ((t & 7) ^ (srow & 7)) * 8;    // source col (elements)
  const bf16* Ag = A + (size_t)(m0 + srow) * K + gcol;
  const bf16* Bg = Bt + (size_t)(n0 + srow) * K + gcol;

  // swizzled fragment read: source granule kh*4+quad at row (..+l16)
  const int fx0 = ((0 * 4 + quad) ^ (l16 & 7)) * 8;
  const int fx1 = ((1 * 4 + quad) ^ (l16 & 7)) * 8;

  for (int k0 = 0; k0 < K; k0 += 64) {
    __syncthreads();
    for (int j = 0; j < BM / 32; j++)
      load_lds16(Ag + (size_t)(j * 32) * K + k0, As + j * 2048 + t * 8);
    for (int j = 0; j < BN / 32; j++)
      load_lds16(Bg + (size_t)(j * 32) * K + k0, Bs + j * 2048 + t * 8);
    __syncthreads();
    for (int kh = 0; kh < 2; kh++) {
      const int fx = kh ? fx1 : fx0;
      bf16x8 af[MI], bfr[NI];
      for (int i = 0; i < MI; i++)
        af[i] = *(const bf16x8*)(As + (wm + i * 16 + l16) * 64 + fx);
      for (int i = 0; i < NI; i++)
        bfr[i] = *(const bf16x8*)(Bs + (wn + i * 16 + l16) * 64 + fx);
      for (int mi = 0; mi < MI; mi++)
        for (int ni = 0; ni < NI; ni++)
          acc[mi][ni] = __builtin_amdgcn_mfma_f32_16x16x32_bf16(
              af[mi], bfr[ni], acc[mi][ni], 0, 0, 0);
    }
  }

  const bool isV = (MODE == 2) && (n0 >= 2 * D_DIM);
  for (int mi = 0; mi < MI; mi++) {
    for (int ni = 0; ni < NI; ni++) {
      const int col = n0 + wn + ni * 16 + l16;
      const float bv = bias ? bias[col] : 0.0f;
      const int row0 = m0 + wm + mi * 16 + quad * 4;
      if (isV) {
        uint32_t w0 = pack_bf16(acc[mi][ni][0] + bv, acc[mi][ni][1] + bv);
        uint32_t w1 = pack_bf16(acc[mi][ni][2] + bv, acc[mi][ni][3] + bv);
        uint2 wv; wv.x = w0; wv.y = w1;
        *(uint2*)(VtOut + (size_t)(col - 2 * D_DIM) * S_LEN + row0) = wv;
      } else {
        for (int r = 0; r < 4; r++) {
          float v = acc[mi][ni][r] + bv;
          if (MODE == 0)
            ((float*)Cout)[(size_t)(row0 + r) * N + col] = v;
          else
            ((bf16*)Cout)[(size_t)(row0 + r) * N + col] = f2bf(v);
        }
      }
    }
  }
}

// ---------------------------------------------------------------------------
// Split-K flash attention, S^T orientation, 128-query blocks, no-max softmax,
// rowsum via ones-MFMA. 1D grid of 640 active blocks: id = rank*16 + h pins
// each head to one XCD (id%8 = h%8). rank -> (qt,c) heavy-first.
// ---------------------------------------------------------------------------
__global__ __launch_bounds__(256) void attn_kernel(
    const bf16* __restrict__ qkv, const bf16* __restrict__ Vt,
    bf16* __restrict__ Opart, float* __restrict__ ml) {
  __shared__ bf16 Qs[128 * 64];     // [query][d] swizzled, 16 KB
  __shared__ bf16 Ks[2][64 * 64];   // [key][d] swizzled, 2x8 KB
  __shared__ bf16 Vs[2][64 * 64];   // [d][key] swizzled, 2x8 KB

  const int t = threadIdx.x;
  const int wave = t >> 6;
  const int lane = t & 63;
  const int quad = lane >> 4;
  const int l16 = lane & 15;
  const int h = blockIdx.x & 15;
  const int rank = blockIdx.x >> 4;  // [0,40), heavy-first
  int qt = 15, c = 0;
  {
    int acc = 0;
    for (int q = 15; q >= 0; q--) {
      const int n = (q >> 2) + 1;
      if (rank < acc + n) { qt = q; c = rank - acc; break; }
      acc += n;
    }
  }
  const int kt0 = c * CHUNK;
  const int kt1 = min(kt0 + CHUNK, 2 * qt + 2);
  const float SC = 0.022097086912079608f;      // 1/sqrt(2048)

  const int srow = t >> 3;
  const int gcol = (((t & 7) ^ (srow & 7))) * 8;

  for (int j = 0; j < 4; j++)  // Q tile: 128 rows in 4 rounds of 32
    load_lds16(
        qkv + (size_t)(qt * 128 + j * 32 + srow) * (3 * D_DIM) + h * HS + gcol,
        Qs + j * 2048 + t * 8);

  auto issueKV = [&](int kt, int b) {
    const bf16* gk =
        qkv + (size_t)(kt * 64 + srow) * (3 * D_DIM) + D_DIM + h * HS + gcol;
    load_lds16(gk, Ks[b] + t * 8);
    load_lds16(gk + (size_t)32 * (3 * D_DIM), Ks[b] + t * 8 + 32 * 64);
    const bf16* gv = Vt + (size_t)(h * HS + srow) * S_LEN + kt * 64 + gcol;
    load_lds16(gv, Vs[b] + t * 8);
    load_lds16(gv + (size_t)32 * S_LEN, Vs[b] + t * 8 + 32 * 64);
  };
  issueKV(kt0, 0);
  __syncthreads();  // drains Q + KV(kt0)

  const int px = (quad ^ (l16 & 7)) * 8;
  bf16x8 bq[2][2];
  int Qb[2], qglob[2];
  for (int sq = 0; sq < 2; sq++) {
    const int qr = (2 * wave + sq) * 16 + l16;
    bq[sq][0] = *(const bf16x8*)(Qs + qr * 64 + px);
    bq[sq][1] = *(const bf16x8*)(Qs + qr * 64 + (px ^ 32));
    Qb[sq] = qt * 128 + (2 * wave + sq) * 16;
    qglob[sq] = Qb[sq] + l16;
  }

  // bpermute byte-indices for P^T C-layout -> B-frag
  int bpidx[4];
  for (int dw = 0; dw < 4; dw++)
    bpidx[dw] = ((((quad & 1) * 2 + (dw >> 1)) * 16 + l16) << 2);
  const bool sel_hi = (quad >> 1) != 0;

  const bf16 one_bf = f2bf(1.0f);
  const bf16x8 ones = {one_bf, one_bf, one_bf, one_bf,
                       one_bf, one_bf, one_bf, one_bf};

  f32x4 o[2][4], ol[2];
  for (int sq = 0; sq < 2; sq++) {
    for (int dt = 0; dt < 4; dt++)
      for (int r = 0; r < 4; r++) o[sq][dt][r] = 0.f;
    for (int r = 0; r < 4; r++) ol[sq][r] = 0.f;
  }

  for (int kt = kt0; kt < kt1; kt++) {
    const int b = (kt - kt0) & 1;
    if (kt > kt0) __syncthreads();  // drains prefetched KV(kt)
    if (kt + 1 < kt1) issueKV(kt + 1, b ^ 1);

    // ---- S^T = K Q^T ----
    f32x4 st[2][4];
    for (int sq = 0; sq < 2; sq++)
      for (int nt = 0; nt < 4; nt++)
        for (int r = 0; r < 4; r++) st[sq][nt][r] = 0.f;
    for (int nt = 0; nt < 4; nt++) {
      bf16x8 ak0 = *(const bf16x8*)(Ks[b] + (nt * 16 + l16) * 64 + px);
      bf16x8 ak1 = *(const bf16x8*)(Ks[b] + (nt * 16 + l16) * 64 + (px ^ 32));
      for (int sq = 0; sq < 2; sq++) {
        st[sq][nt] =
            __builtin_amdgcn_mfma_f32_16x16x32_bf16(ak0, bq[sq][0], st[sq][nt], 0, 0, 0);
        st[sq][nt] =
            __builtin_amdgcn_mfma_f32_16x16x32_bf16(ak1, bq[sq][1], st[sq][nt], 0, 0, 0);
      }
    }

    // ---- p = exp(s*SC) (no max), causal mask -> 0, pack to bf16 ----
    uint32_t pk[2][4][2];
    for (int sq = 0; sq < 2; sq++) {
      float p[4][4];
      if (kt * 64 + 63 > Qb[sq]) {  // tile touches/exceeds diagonal
        for (int nt = 0; nt < 4; nt++)
          for (int r = 0; r < 4; r++) {
            const int key = kt * 64 + nt * 16 + quad * 4 + r;
            p[nt][r] = (key <= qglob[sq]) ? __expf(st[sq][nt][r] * SC) : 0.f;
          }
      } else {
        for (int nt = 0; nt < 4; nt++)
          for (int r = 0; r < 4; r++) p[nt][r] = __expf(st[sq][nt][r] * SC);
      }
      for (int nt = 0; nt < 4; nt++) {
        pk[sq][nt][0] = pack_bf16(p[nt][0], p[nt][1]);
        pk[sq][nt][1] = pack_bf16(p[nt][2], p[nt][3]);
      }
    }

    // ---- P^T B-frags via bpermute; O^T += V^T P^T; rowsum via ones-MFMA ----
    for (int half = 0; half < 2; half++) {
      bf16x8 bpv[2];
      for (int sq = 0; sq < 2; sq++) {
        uint32_t dwv[4];
        for (int dw = 0; dw < 4; dw++) {
          int f0 = __builtin_amdgcn_ds_bpermute(bpidx[dw],
                                                (int)pk[sq][half * 2 + 0][dw & 1]);
          int f1 = __builtin_amdgcn_ds_bpermute(bpidx[dw],
                                                (int)pk[sq][half * 2 + 1][dw & 1]);
          dwv[dw] = (uint32_t)(sel_hi ? f1 : f0);
        }
        union { uint32_t u[4]; bf16x8 v; } u_;
        u_.u[0] = dwv[0]; u_.u[1] = dwv[1]; u_.u[2] = dwv[2]; u_.u[3] = dwv[3];
        bpv[sq] = u_.v;
      }
      const int vpx = half ? (px ^ 32) : px;
      for (int dt = 0; dt < 4; dt++) {
        bf16x8 av = *(const bf16x8*)(Vs[b] + (dt * 16 + l16) * 64 + vpx);
        o[0][dt] = __builtin_amdgcn_mfma_f32_16x16x32_bf16(av, bpv[0], o[0][dt], 0, 0, 0);
        o[1][dt] = __builtin_amdgcn_mfma_f32_16x16x32_bf16(av, bpv[1], o[1][dt], 0, 0, 0);
      }
      ol[0] = __builtin_amdgcn_mfma_f32_16x16x32_bf16(ones, bpv[0], ol[0], 0, 0, 0);
      ol[1] = __builtin_amdgcn_mfma_f32_16x16x32_bf16(ones, bpv[1], ol[1], 0, 0, 0);
    }
  }

  // ---- epilogue: normalized partial (bf16) + l (from ones-MFMA) ----
  for (int sq = 0; sq < 2; sq++) {
    const float l_v = ol[sq][0];
    const float inv_l = 1.0f / l_v;
    const int qrow = Qb[sq] + l16;
    const size_t pbase = (((size_t)c * NH + h) * S_LEN + qrow) * 64;
    for (int dt = 0; dt < 4; dt++) {
      uint32_t w0 = pack_bf16(o[sq][dt][0] * inv_l, o[sq][dt][1] * inv_l);
      uint32_t w1 = pack_bf16(o[sq][dt][2] * inv_l, o[sq][dt][3] * inv_l);
      uint2 wv; wv.x = w0; wv.y = w1;
      *(uint2*)(Opart + pbase + dt * 16 + quad * 4) = wv;
    }
    if (quad == 0) ml[((size_t)c * NH + h) * S_LEN + qrow] = l_v;
  }
}

// ---------------------------------------------------------------------------
// Combine: one wave per (h, qrow); lane = d; weights = l_c.
// ---------------------------------------------------------------------------
__global__ __launch_bounds__(256) void combine_kernel(
    const bf16* __restrict__ Opart, const float* __restrict__ ml,
    bf16* __restrict__ Obf) {
  const int wave = threadIdx.x >> 6;
  const int lane = threadIdx.x & 63;
  const int idx = blockIdx.x * 4 + wave;  // h*2048 + qrow
  const int h = idx >> 11;
  const int qrow = idx & 2047;
  const int nc = (qrow >> 6) / CHUNK + 1;

  float aw = 0.f, ao = 0.f;
  for (int cix = 0; cix < nc; cix++) {
    const float w = ml[((size_t)cix * NH + h) * S_LEN + qrow];
    aw += w;
    ao += w * (float)Opart[(((size_t)cix * NH + h) * S_LEN + qrow) * 64 + lane];
  }
  Obf[(size_t)qrow * D_DIM + h * HS + lane] = f2bf(ao / aw);
}

// ---------------------------------------------------------------------------
extern "C" void kernel_launch(void* const* d_in, const int* in_sizes, int n_in,
                              void* d_out, int out_size, void* d_ws,
                              size_t ws_size, hipStream_t stream) {
  const float* hs = (const float*)d_in[0];   // [2048][1024]
  const float* Wa = (const float*)d_in[1];   // [1024][3072]
  const float* ba = (const float*)d_in[2];   // [3072]
  const float* Wp = (const float*)d_in[3];   // [1024][1024]
  const float* bp = (const float*)d_in[4];   // [1024]
  float* out = (float*)d_out;                // [2048][1024]

  char* ws = (char*)d_ws;
  bf16* hsb   = (bf16*)(ws);                    // 4 MB  [2048][1024]
  bf16* WaT   = (bf16*)(ws + (4ull << 20));     // 6 MB  [3072][1024]
  bf16* WpT   = (bf16*)(ws + (10ull << 20));    // 2 MB  [1024][1024]
  bf16* qkv   = (bf16*)(ws + (12ull << 20));    // 12 MB [2048][3072] (Q,K used)
  bf16* Vt    = (bf16*)(ws + (24ull << 20));    // 4 MB  [1024][2048]
  bf16* Obf   = (bf16*)(ws + (28ull << 20));    // 4 MB  [2048][1024]
  bf16* Opart = (bf16*)(ws + (32ull << 20));    // 16 MB [4][16][2048][64]
  float* mlp  = (float*)(ws + (48ull << 20));   // 0.5MB [4][16][2048]

  // prep: cast hs (2048 blocks) + transpose both weights (4096 blocks)
  prep_kernel<<<6144, 256, 0, stream>>>(hs, Wa, Wp, hsb, WaT, WpT);
  // qkv = hs @ W_attn + b_attn; V columns land transposed in Vt
  gemm_bt_kernel<128, 128, 2><<<dim3(3 * D_DIM / 128, S_LEN / 128), 256, 0,
                                stream>>>(hsb, WaT, ba, qkv, Vt, S_LEN,
                                          3 * D_DIM, D_DIM);
  // split-K flash attention: 640 active blocks, heads pinned to XCDs
  attn_kernel<<<640, 256, 0, stream>>>(qkv, Vt, Opart, mlp);
  combine_kernel<<<(S_LEN * NH) / 4, 256, 0, stream>>>(Opart, mlp, Obf);
  // out = Obf @ W_proj + b_proj (fp32): 128x64 tiles -> 256 blocks
  gemm_bt_kernel<128, 64, 0><<<dim3(D_DIM / 64, S_LEN / 128), 256, 0, stream>>>(
      Obf, WpT, bp, out, nullptr, S_LEN, D_DIM, D_DIM);

  (void)in_sizes; (void)n_in; (void)out_size; (void)ws_size;
}

// Round 7
// 142.380 us; speedup vs baseline: 1.0814x; 1.0814x over previous
//
#include <hip/hip_runtime.h>
#include <cstdint>

// ---------------------------------------------------------------------------
// CausalSelfAttention: S=2048, D=1024, H=16, HS=64
// Split-K flash attention (S^T orientation, 128-query blocks, no-max softmax,
// ones-MFMA rowsum, double-buffered K/V, XOR-swizzled LDS, head->XCD pinning)
// + bf16 MFMA GEMMs (BK=64, swizzled LDS, occupancy-exact grids).
// ---------------------------------------------------------------------------

typedef __bf16 bf16;
typedef __attribute__((ext_vector_type(4))) float f32x4;
typedef __attribute__((ext_vector_type(8))) bf16 bf16x8;
typedef __attribute__((ext_vector_type(4))) bf16 bf16x4;

#define S_LEN 2048
#define D_DIM 1024
#define NH 16
#define HS 64
#define CHUNK 8          // K-tiles (of 64 keys) per split-K chunk
#define NCK 4            // max chunks = 32 ktiles / CHUNK

__device__ __forceinline__ bf16 f2bf(float f) {
  uint32_t u = __builtin_bit_cast(uint32_t, f);
  uint32_t r = (u + 0x7FFFu + ((u >> 16) & 1u)) >> 16;
  unsigned short s = (unsigned short)r;
  return __builtin_bit_cast(bf16, s);
}

__device__ __forceinline__ void load_lds16(const void* g, void* l) {
  __builtin_amdgcn_global_load_lds(
      (__attribute__((address_space(1))) unsigned int*)(uintptr_t)g,
      (__attribute__((address_space(3))) unsigned int*)l, 16, 0, 0);
}

// pack two fp32 -> bf16 pair with round-half-up: (hi<<16)|lo
__device__ __forceinline__ uint32_t pack_bf16(float lo, float hi) {
  uint32_t a = __builtin_bit_cast(uint32_t, lo) + 0x8000u;
  uint32_t b = __builtin_bit_cast(uint32_t, hi) + 0x8000u;
  return __builtin_amdgcn_perm(b, a, 0x07060302u);
}

// ---------------------------------------------------------------------------
// Fused prep: blocks [0,2048): cast hs -> hsb (bf16)
//             blocks [2048,6144): transpose+cast W_attn / W_proj
// ---------------------------------------------------------------------------
__global__ __launch_bounds__(256) void prep_kernel(
    const float* __restrict__ hs, const float* __restrict__ Wa,
    const float* __restrict__ Wp, bf16* __restrict__ hsb,
    bf16* __restrict__ WaT, bf16* __restrict__ WpT) {
  const int bid = blockIdx.x;
  if (bid < 2048) {
    const int i = bid * 256 + threadIdx.x;
    float4 v = ((const float4*)hs)[i];
    bf16x4 o;
    o[0] = f2bf(v.x); o[1] = f2bf(v.y); o[2] = f2bf(v.z); o[3] = f2bf(v.w);
    ((bf16x4*)hsb)[i] = o;
    return;
  }
  __shared__ float tile[32][33];
  const int tb = bid - 2048;          // [0,4096)
  const int bx = tb & 127;            // col-tile: Wa 0..95, Wp 96..127
  const int r0 = (tb >> 7) * 32;      // row-tile (R = 1024 both)
  const bool isA = bx < 96;
  const float* in = isA ? Wa : Wp;
  bf16* out = isA ? WaT : WpT;
  const int C = isA ? 3072 : 1024;
  const int c0 = (isA ? bx : bx - 96) * 32;
  const int x = threadIdx.x & 31, y = threadIdx.x >> 5;
  for (int k = 0; k < 32; k += 8)
    tile[y + k][x] = in[(size_t)(r0 + y + k) * C + c0 + x];
  __syncthreads();
  for (int k = 0; k < 32; k += 8)
    out[(size_t)(c0 + y + k) * 1024 + r0 + x] = f2bf(tile[x][y + k]);
}

// ---------------------------------------------------------------------------
// GEMM: C[M][N] = A[M][K] * Bt[N][K]^T + bias[N].  BK=64, XOR-swizzled LDS
// (16B granule slot g holds source granule g^(row&7) -> 2-way reads, free).
// MODE 0: fp32 out. MODE 2: bf16 qkv out, but blocks with n0 >= 2*D_DIM write
// V transposed into VtOut[col-2048][row] instead.
// Wave layout: BN=128 -> 2x2 waves of 64x64 (MI=4). BN=64 -> 4x1 waves
// stacked in M: BM=128 -> 32 rows/wave (MI=2); BM=64 -> 16 rows/wave (MI=1).
// ---------------------------------------------------------------------------
template <int BM, int BN, int MODE>
__global__ __launch_bounds__(256) void gemm_bt_kernel(
    const bf16* __restrict__ A, const bf16* __restrict__ Bt,
    const float* __restrict__ bias, void* __restrict__ Cout,
    bf16* __restrict__ VtOut, int M, int N, int K) {
  constexpr int MI = (BN == 128) ? 4 : (BM == 128 ? 2 : 1);
  constexpr int NI = 4;
  __shared__ bf16 As[BM * 64];
  __shared__ bf16 Bs[BN * 64];
  const int t = threadIdx.x;
  const int wave = t >> 6;
  const int lane = t & 63;
  const int quad = lane >> 4;
  const int l16 = lane & 15;
  const int m0 = blockIdx.y * BM;
  const int n0 = blockIdx.x * BN;
  const int wm = (BN == 128) ? (wave >> 1) * 64 : wave * (16 * MI);
  const int wn = (BN == 128) ? (wave & 1) * 64 : 0;

  f32x4 acc[MI][NI];
  for (int i = 0; i < MI; i++)
    for (int j = 0; j < NI; j++)
      for (int r = 0; r < 4; r++) acc[i][j][r] = 0.f;

  // staging: 8 threads/row of 64 cols, 32 rows per issue, swizzled source col
  const int srow = t >> 3;                        // 0..31
  const int gcol = ((t & 7) ^ (srow & 7)) * 8;    // source col (elements)
  const bf16* Ag = A + (size_t)(m0 + srow) * K + gcol;
  const bf16* Bg = Bt + (size_t)(n0 + srow) * K + gcol;

  // swizzled fragment read: source granule kh*4+quad at row (..+l16)
  const int fx0 = ((0 * 4 + quad) ^ (l16 & 7)) * 8;
  const int fx1 = ((1 * 4 + quad) ^ (l16 & 7)) * 8;

  for (int k0 = 0; k0 < K; k0 += 64) {
    __syncthreads();
    for (int j = 0; j < BM / 32; j++)
      load_lds16(Ag + (size_t)(j * 32) * K + k0, As + j * 2048 + t * 8);
    for (int j = 0; j < BN / 32; j++)
      load_lds16(Bg + (size_t)(j * 32) * K + k0, Bs + j * 2048 + t * 8);
    __syncthreads();
    for (int kh = 0; kh < 2; kh++) {
      const int fx = kh ? fx1 : fx0;
      bf16x8 af[MI], bfr[NI];
      for (int i = 0; i < MI; i++)
        af[i] = *(const bf16x8*)(As + (wm + i * 16 + l16) * 64 + fx);
      for (int i = 0; i < NI; i++)
        bfr[i] = *(const bf16x8*)(Bs + (wn + i * 16 + l16) * 64 + fx);
      for (int mi = 0; mi < MI; mi++)
        for (int ni = 0; ni < NI; ni++)
          acc[mi][ni] = __builtin_amdgcn_mfma_f32_16x16x32_bf16(
              af[mi], bfr[ni], acc[mi][ni], 0, 0, 0);
    }
  }

  const bool isV = (MODE == 2) && (n0 >= 2 * D_DIM);
  for (int mi = 0; mi < MI; mi++) {
    for (int ni = 0; ni < NI; ni++) {
      const int col = n0 + wn + ni * 16 + l16;
      const float bv = bias ? bias[col] : 0.0f;
      const int row0 = m0 + wm + mi * 16 + quad * 4;
      if (isV) {
        uint32_t w0 = pack_bf16(acc[mi][ni][0] + bv, acc[mi][ni][1] + bv);
        uint32_t w1 = pack_bf16(acc[mi][ni][2] + bv, acc[mi][ni][3] + bv);
        uint2 wv; wv.x = w0; wv.y = w1;
        *(uint2*)(VtOut + (size_t)(col - 2 * D_DIM) * S_LEN + row0) = wv;
      } else {
        for (int r = 0; r < 4; r++) {
          float v = acc[mi][ni][r] + bv;
          if (MODE == 0)
            ((float*)Cout)[(size_t)(row0 + r) * N + col] = v;
          else
            ((bf16*)Cout)[(size_t)(row0 + r) * N + col] = f2bf(v);
        }
      }
    }
  }
}

// ---------------------------------------------------------------------------
// Split-K flash attention, S^T orientation, 128-query blocks, no-max softmax,
// rowsum via ones-MFMA. 1D grid of 640 active blocks: id = rank*16 + h pins
// each head to one XCD (id%8 = h%8). rank -> (qt,c) heavy-first.
// ---------------------------------------------------------------------------
__global__ __launch_bounds__(256) void attn_kernel(
    const bf16* __restrict__ qkv, const bf16* __restrict__ Vt,
    bf16* __restrict__ Opart, float* __restrict__ ml) {
  __shared__ bf16 Qs[128 * 64];     // [query][d] swizzled, 16 KB
  __shared__ bf16 Ks[2][64 * 64];   // [key][d] swizzled, 2x8 KB
  __shared__ bf16 Vs[2][64 * 64];   // [d][key] swizzled, 2x8 KB

  const int t = threadIdx.x;
  const int wave = t >> 6;
  const int lane = t & 63;
  const int quad = lane >> 4;
  const int l16 = lane & 15;
  const int h = blockIdx.x & 15;
  const int rank = blockIdx.x >> 4;  // [0,40), heavy-first
  int qt = 15, c = 0;
  {
    int acc = 0;
    for (int q = 15; q >= 0; q--) {
      const int n = (q >> 2) + 1;
      if (rank < acc + n) { qt = q; c = rank - acc; break; }
      acc += n;
    }
  }
  const int kt0 = c * CHUNK;
  const int kt1 = min(kt0 + CHUNK, 2 * qt + 2);
  const float SC = 0.022097086912079608f;      // 1/sqrt(2048)

  const int srow = t >> 3;
  const int gcol = (((t & 7) ^ (srow & 7))) * 8;

  for (int j = 0; j < 4; j++)  // Q tile: 128 rows in 4 rounds of 32
    load_lds16(
        qkv + (size_t)(qt * 128 + j * 32 + srow) * (3 * D_DIM) + h * HS + gcol,
        Qs + j * 2048 + t * 8);

  auto issueKV = [&](int kt, int b) {
    const bf16* gk =
        qkv + (size_t)(kt * 64 + srow) * (3 * D_DIM) + D_DIM + h * HS + gcol;
    load_lds16(gk, Ks[b] + t * 8);
    load_lds16(gk + (size_t)32 * (3 * D_DIM), Ks[b] + t * 8 + 32 * 64);
    const bf16* gv = Vt + (size_t)(h * HS + srow) * S_LEN + kt * 64 + gcol;
    load_lds16(gv, Vs[b] + t * 8);
    load_lds16(gv + (size_t)32 * S_LEN, Vs[b] + t * 8 + 32 * 64);
  };
  issueKV(kt0, 0);
  __syncthreads();  // drains Q + KV(kt0)

  const int px = (quad ^ (l16 & 7)) * 8;
  bf16x8 bq[2][2];
  int Qb[2], qglob[2];
  for (int sq = 0; sq < 2; sq++) {
    const int qr = (2 * wave + sq) * 16 + l16;
    bq[sq][0] = *(const bf16x8*)(Qs + qr * 64 + px);
    bq[sq][1] = *(const bf16x8*)(Qs + qr * 64 + (px ^ 32));
    Qb[sq] = qt * 128 + (2 * wave + sq) * 16;
    qglob[sq] = Qb[sq] + l16;
  }

  // bpermute byte-indices for P^T C-layout -> B-frag
  int bpidx[4];
  for (int dw = 0; dw < 4; dw++)
    bpidx[dw] = ((((quad & 1) * 2 + (dw >> 1)) * 16 + l16) << 2);
  const bool sel_hi = (quad >> 1) != 0;

  const bf16 one_bf = f2bf(1.0f);
  const bf16x8 ones = {one_bf, one_bf, one_bf, one_bf,
                       one_bf, one_bf, one_bf, one_bf};

  f32x4 o[2][4], ol[2];
  for (int sq = 0; sq < 2; sq++) {
    for (int dt = 0; dt < 4; dt++)
      for (int r = 0; r < 4; r++) o[sq][dt][r] = 0.f;
    for (int r = 0; r < 4; r++) ol[sq][r] = 0.f;
  }

  for (int kt = kt0; kt < kt1; kt++) {
    const int b = (kt - kt0) & 1;
    if (kt > kt0) __syncthreads();  // drains prefetched KV(kt)
    if (kt + 1 < kt1) issueKV(kt + 1, b ^ 1);

    // ---- S^T = K Q^T ----
    f32x4 st[2][4];
    for (int sq = 0; sq < 2; sq++)
      for (int nt = 0; nt < 4; nt++)
        for (int r = 0; r < 4; r++) st[sq][nt][r] = 0.f;
    for (int nt = 0; nt < 4; nt++) {
      bf16x8 ak0 = *(const bf16x8*)(Ks[b] + (nt * 16 + l16) * 64 + px);
      bf16x8 ak1 = *(const bf16x8*)(Ks[b] + (nt * 16 + l16) * 64 + (px ^ 32));
      for (int sq = 0; sq < 2; sq++) {
        st[sq][nt] =
            __builtin_amdgcn_mfma_f32_16x16x32_bf16(ak0, bq[sq][0], st[sq][nt], 0, 0, 0);
        st[sq][nt] =
            __builtin_amdgcn_mfma_f32_16x16x32_bf16(ak1, bq[sq][1], st[sq][nt], 0, 0, 0);
      }
    }

    // ---- p = exp(s*SC) (no max), causal mask -> 0, pack to bf16 ----
    uint32_t pk[2][4][2];
    for (int sq = 0; sq < 2; sq++) {
      float p[4][4];
      if (kt * 64 + 63 > Qb[sq]) {  // tile touches/exceeds diagonal
        for (int nt = 0; nt < 4; nt++)
          for (int r = 0; r < 4; r++) {
            const int key = kt * 64 + nt * 16 + quad * 4 + r;
            p[nt][r] = (key <= qglob[sq]) ? __expf(st[sq][nt][r] * SC) : 0.f;
          }
      } else {
        for (int nt = 0; nt < 4; nt++)
          for (int r = 0; r < 4; r++) p[nt][r] = __expf(st[sq][nt][r] * SC);
      }
      for (int nt = 0; nt < 4; nt++) {
        pk[sq][nt][0] = pack_bf16(p[nt][0], p[nt][1]);
        pk[sq][nt][1] = pack_bf16(p[nt][2], p[nt][3]);
      }
    }

    // ---- P^T B-frags via bpermute; O^T += V^T P^T; rowsum via ones-MFMA ----
    for (int half = 0; half < 2; half++) {
      bf16x8 bpv[2];
      for (int sq = 0; sq < 2; sq++) {
        uint32_t dwv[4];
        for (int dw = 0; dw < 4; dw++) {
          int f0 = __builtin_amdgcn_ds_bpermute(bpidx[dw],
                                                (int)pk[sq][half * 2 + 0][dw & 1]);
          int f1 = __builtin_amdgcn_ds_bpermute(bpidx[dw],
                                                (int)pk[sq][half * 2 + 1][dw & 1]);
          dwv[dw] = (uint32_t)(sel_hi ? f1 : f0);
        }
        union { uint32_t u[4]; bf16x8 v; } u_;
        u_.u[0] = dwv[0]; u_.u[1] = dwv[1]; u_.u[2] = dwv[2]; u_.u[3] = dwv[3];
        bpv[sq] = u_.v;
      }
      const int vpx = half ? (px ^ 32) : px;
      for (int dt = 0; dt < 4; dt++) {
        bf16x8 av = *(const bf16x8*)(Vs[b] + (dt * 16 + l16) * 64 + vpx);
        o[0][dt] = __builtin_amdgcn_mfma_f32_16x16x32_bf16(av, bpv[0], o[0][dt], 0, 0, 0);
        o[1][dt] = __builtin_amdgcn_mfma_f32_16x16x32_bf16(av, bpv[1], o[1][dt], 0, 0, 0);
      }
      ol[0] = __builtin_amdgcn_mfma_f32_16x16x32_bf16(ones, bpv[0], ol[0], 0, 0, 0);
      ol[1] = __builtin_amdgcn_mfma_f32_16x16x32_bf16(ones, bpv[1], ol[1], 0, 0, 0);
    }
  }

  // ---- epilogue: normalized partial (bf16) + l (from ones-MFMA) ----
  for (int sq = 0; sq < 2; sq++) {
    const float l_v = ol[sq][0];
    const float inv_l = 1.0f / l_v;
    const int qrow = Qb[sq] + l16;
    const size_t pbase = (((size_t)c * NH + h) * S_LEN + qrow) * 64;
    for (int dt = 0; dt < 4; dt++) {
      uint32_t w0 = pack_bf16(o[sq][dt][0] * inv_l, o[sq][dt][1] * inv_l);
      uint32_t w1 = pack_bf16(o[sq][dt][2] * inv_l, o[sq][dt][3] * inv_l);
      uint2 wv; wv.x = w0; wv.y = w1;
      *(uint2*)(Opart + pbase + dt * 16 + quad * 4) = wv;
    }
    if (quad == 0) ml[((size_t)c * NH + h) * S_LEN + qrow] = l_v;
  }
}

// ---------------------------------------------------------------------------
// Combine: one wave per (h, qrow); lane = d; weights = l_c.
// ---------------------------------------------------------------------------
__global__ __launch_bounds__(256) void combine_kernel(
    const bf16* __restrict__ Opart, const float* __restrict__ ml,
    bf16* __restrict__ Obf) {
  const int wave = threadIdx.x >> 6;
  const int lane = threadIdx.x & 63;
  const int idx = blockIdx.x * 4 + wave;  // h*2048 + qrow
  const int h = idx >> 11;
  const int qrow = idx & 2047;
  const int nc = (qrow >> 6) / CHUNK + 1;

  float aw = 0.f, ao = 0.f;
  for (int cix = 0; cix < nc; cix++) {
    const float w = ml[((size_t)cix * NH + h) * S_LEN + qrow];
    aw += w;
    ao += w * (float)Opart[(((size_t)cix * NH + h) * S_LEN + qrow) * 64 + lane];
  }
  Obf[(size_t)qrow * D_DIM + h * HS + lane] = f2bf(ao / aw);
}

// ---------------------------------------------------------------------------
extern "C" void kernel_launch(void* const* d_in, const int* in_sizes, int n_in,
                              void* d_out, int out_size, void* d_ws,
                              size_t ws_size, hipStream_t stream) {
  const float* hs = (const float*)d_in[0];   // [2048][1024]
  const float* Wa = (const float*)d_in[1];   // [1024][3072]
  const float* ba = (const float*)d_in[2];   // [3072]
  const float* Wp = (const float*)d_in[3];   // [1024][1024]
  const float* bp = (const float*)d_in[4];   // [1024]
  float* out = (float*)d_out;                // [2048][1024]

  char* ws = (char*)d_ws;
  bf16* hsb   = (bf16*)(ws);                    // 4 MB  [2048][1024]
  bf16* WaT   = (bf16*)(ws + (4ull << 20));     // 6 MB  [3072][1024]
  bf16* WpT   = (bf16*)(ws + (10ull << 20));    // 2 MB  [1024][1024]
  bf16* qkv   = (bf16*)(ws + (12ull << 20));    // 12 MB [2048][3072] (Q,K used)
  bf16* Vt    = (bf16*)(ws + (24ull << 20));    // 4 MB  [1024][2048]
  bf16* Obf   = (bf16*)(ws + (28ull << 20));    // 4 MB  [2048][1024]
  bf16* Opart = (bf16*)(ws + (32ull << 20));    // 16 MB [4][16][2048][64]
  float* mlp  = (float*)(ws + (48ull << 20));   // 0.5MB [4][16][2048]

  // prep: cast hs (2048 blocks) + transpose both weights (4096 blocks)
  prep_kernel<<<6144, 256, 0, stream>>>(hs, Wa, Wp, hsb, WaT, WpT);
  // qkv = hs @ W_attn + b_attn; V columns land transposed in Vt
  // 128x64 tiles -> 48x16 = 768 blocks = exactly 3/CU (LDS 24KB, cap 6/CU)
  gemm_bt_kernel<128, 64, 2><<<dim3(3 * D_DIM / 64, S_LEN / 128), 256, 0,
                               stream>>>(hsb, WaT, ba, qkv, Vt, S_LEN,
                                         3 * D_DIM, D_DIM);
  // split-K flash attention: 640 active blocks, heads pinned to XCDs
  attn_kernel<<<640, 256, 0, stream>>>(qkv, Vt, Opart, mlp);
  combine_kernel<<<(S_LEN * NH) / 4, 256, 0, stream>>>(Opart, mlp, Obf);
  // out = Obf @ W_proj + b_proj (fp32): 64x64 tiles -> 16x32 = 512 blocks
  gemm_bt_kernel<64, 64, 0><<<dim3(D_DIM / 64, S_LEN / 64), 256, 0, stream>>>(
      Obf, WpT, bp, out, nullptr, S_LEN, D_DIM, D_DIM);

  (void)in_sizes; (void)n_in; (void)out_size; (void)ws_size;
}